// Round 15
// baseline (199.899 us; speedup 1.0000x reference)
//
#include <hip/hip_runtime.h>
#include <hip/hip_fp16.h>

// ---------------------------------------------------------------------------
// 2-layer GCN: fused atomic-claim CSR build + 16-lane-group gathers.
//   out = dinv * (A (relu((dinv*(A' xs)) W1 + b1) W2 * dinv)) + b2
// xs = x*dinv stored FP16 in 32B rows (3.2MB, per-XCD-L2-resident gathers).
// scatterB fuses {dst-histogram, per-bucket space claim, scatter} per
// contiguous 25600-edge chunk: dst is read ONCE (cached in LDS as u16 low
// bits + ballot bit-16 bitmap; n_nodes < 2^17), claims are 64B-aligned via
// global atomicAdd on fixed-capacity bucket regions (cap = 1.25*mean+2048,
// ~48 sigma slack, store-clamped) -> no histA array, no scan kernels, no
// cross-XCD false sharing (R10/R11 lesson), edge traffic 153->102MB.
// Edge packed: src | (local_dst << 24).
// ---------------------------------------------------------------------------

#define BKT_BITS  8
#define BKT_SZ    256       // nodes per bucket
#define NBK       512       // padded bucket slots (>= n buckets)
#define TPB_A     1024      // threads per block in scatterB
#define TPB_B     1024      // threads per block in passB
#define CHUNK     25600     // edges per scatterB block (25 x 1024)
#define NIT       (CHUNK / TPB_A)
#define DST_SHIFT 24
#define SRC_MASK  0xFFFFFFu
#define XS_BYTES  32        // bytes per xs row (10 fp16 + pad)
#define SENTINEL  0xFFFFFFFFu

static __device__ __forceinline__ int nt_src(const void* ei, int is64, int n_edges, unsigned e) {
    return is64 ? (int)__builtin_nontemporal_load(&((const long long*)ei)[e])
                : __builtin_nontemporal_load(&((const int*)ei)[e]);
}
static __device__ __forceinline__ int nt_dst(const void* ei, int is64, int n_edges, unsigned e) {
    return is64 ? (int)__builtin_nontemporal_load(&((const long long*)ei)[(unsigned)n_edges + e])
                : __builtin_nontemporal_load(&((const int*)ei)[(unsigned)n_edges + e]);
}

static __device__ __forceinline__ float2 h2f(unsigned w) {
    __half2 h = *(__half2*)&w;
    return __half22float2(h);
}

// Detect int64 vs int32 edge encoding; init per-bucket claim cursors.
static __global__ void detect_init_kernel(const unsigned int* __restrict__ w, int* flag,
                                          unsigned* __restrict__ gbase, unsigned cap) {
    __shared__ int nz;
    if (threadIdx.x == 0) nz = 0;
    __syncthreads();
    int local = 0;
    for (int k = threadIdx.x; k < 4096; k += blockDim.x)
        if (w[2 * k + 1] != 0u) local = 1;
    if (local) atomicOr(&nz, 1);
    __syncthreads();
    if (threadIdx.x == 0) *flag = (nz == 0) ? 1 : 0;  // 1 => int64 encoding
    for (int b = threadIdx.x; b < NBK; b += blockDim.x)
        gbase[b] = (unsigned)b * cap;
}

// Fused hist + claim + scatter. One contiguous CHUNK of edges per block.
static __global__ void scatterB_kernel(const void* __restrict__ ei, const int* __restrict__ flag,
                                       unsigned* __restrict__ gbase,
                                       unsigned* __restrict__ bucketed,
                                       int n_edges, unsigned cap) {
    __shared__ unsigned short dlo[CHUNK];       // dst low 16 bits
    __shared__ unsigned dbit[CHUNK / 32];       // dst bit 16 (n_nodes < 2^17)
    __shared__ unsigned h[NBK];
    __shared__ unsigned runbase[NBK];
    __shared__ unsigned cur[NBK];
    const int t = threadIdx.x;
    const unsigned e0 = (unsigned)blockIdx.x * CHUNK;
    const int is64 = *flag;
    for (int i = t; i < NBK; i += TPB_A) h[i] = 0u;
    __syncthreads();
    // subpass 1: read dst once, cache in LDS, histogram
    for (int it = 0; it < NIT; ++it) {
        unsigned idx = (unsigned)it * TPB_A + (unsigned)t;
        unsigned e = e0 + idx;
        bool valid = e < (unsigned)n_edges;
        unsigned d = valid ? (unsigned)nt_dst(ei, is64, n_edges, e) : 0u;
        dlo[idx] = (unsigned short)d;
        unsigned long long m = __ballot((d >> 16) & 1u);
        if ((t & 31) == 0)
            dbit[idx >> 5] = (unsigned)(((t & 63) >= 32) ? (m >> 32) : m);
        if (valid) atomicAdd(&h[d >> BKT_BITS], 1u);
    }
    __syncthreads();
    // claim 64B-aligned space per (block,bucket) run
    for (int b = t; b < NBK; b += TPB_A) {
        unsigned hb = h[b];
        unsigned rb = 0u;
        if (hb) rb = atomicAdd(&gbase[b], (hb + 15u) & ~15u);
        runbase[b] = rb;
        cur[b] = rb;
    }
    __syncthreads();
    // subpass 2: read src only; reconstruct dst from LDS; scatter
    for (int it = 0; it < NIT; ++it) {
        unsigned idx = (unsigned)it * TPB_A + (unsigned)t;
        unsigned e = e0 + idx;
        if (e < (unsigned)n_edges) {
            unsigned s = (unsigned)nt_src(ei, is64, n_edges, e);
            unsigned d = (unsigned)dlo[idx] | (((dbit[idx >> 5] >> (idx & 31u)) & 1u) << 16);
            unsigned b = d >> BKT_BITS;
            unsigned pos = atomicAdd(&cur[b], 1u);
            if (pos < (b + 1u) * cap)   // overflow clamp (~48 sigma, never in practice)
                bucketed[pos] = s | ((d & (BKT_SZ - 1u)) << DST_SHIFT);
        }
    }
    __syncthreads();
    // pad run tails to the 16-edge (64B) boundary with sentinels
    for (int b = t; b < NBK; b += TPB_A) {
        if (!h[b]) continue;
        unsigned rb = runbase[b];
        unsigned lim = (b + 1u) * cap;
        unsigned cu = cur[b]; if (cu > lim) cu = lim;
        unsigned end = rb + ((cu - rb + 15u) & ~15u);
        if (end > lim) end = lim;
        for (unsigned q = cu; q < end; ++q) bucketed[q] = SENTINEL;
    }
}

// Per 256-node bucket: counting sort by local dst (skipping sentinels); emit
// csr_src, row_start, cnt, dinv AND xs = fp16(x*dinv). uint4 reads (runs are
// 16-word padded, base = b*cap with cap%16==0 -> no tail handling).
static __global__ void passB_kernel(const unsigned* __restrict__ bucketed,
                                    const unsigned* __restrict__ gbase, unsigned cap,
                                    const float* __restrict__ x,
                                    unsigned* __restrict__ csr_src,
                                    unsigned* __restrict__ row_start,
                                    unsigned* __restrict__ cnt,
                                    float* __restrict__ dinv,
                                    char* __restrict__ xs, int n_nodes) {
    const int b = blockIdx.x;
    const int n0 = b << BKT_BITS;
    const int t = threadIdx.x;
    const unsigned base = (unsigned)b * cap;
    unsigned gb = gbase[b];
    unsigned lim = base + cap;
    if (gb > lim) gb = lim;
    const unsigned count = gb - base;   // padded count (multiple of 16)

    __shared__ unsigned h4[4][BKT_SZ];
    __shared__ unsigned s0[BKT_SZ], s1[BKT_SZ];
    __shared__ unsigned cur[BKT_SZ];
    for (int i = t; i < 4 * BKT_SZ; i += TPB_B) ((unsigned*)h4)[i] = 0u;
    __syncthreads();
    const int copy = (t >> 8) & 3;
    const uint4* B4 = (const uint4*)(bucketed + base);
    const unsigned nquad = count >> 2;
    for (unsigned q = t; q < nquad; q += TPB_B) {
        uint4 w4 = B4[q];
        if (w4.x != SENTINEL) atomicAdd(&h4[copy][w4.x >> DST_SHIFT], 1u);
        if (w4.y != SENTINEL) atomicAdd(&h4[copy][w4.y >> DST_SHIFT], 1u);
        if (w4.z != SENTINEL) atomicAdd(&h4[copy][w4.z >> DST_SHIFT], 1u);
        if (w4.w != SENTINEL) atomicAdd(&h4[copy][w4.w >> DST_SHIFT], 1u);
    }
    __syncthreads();
    unsigned hv = 0;
    unsigned* a = s0; unsigned* c = s1;
    if (t < BKT_SZ) {
        hv = h4[0][t] + h4[1][t] + h4[2][t] + h4[3][t];
        a[t] = hv;
    }
    __syncthreads();
    for (int off = 1; off < BKT_SZ; off <<= 1) {
        if (t < BKT_SZ) c[t] = a[t] + (t >= off ? a[t - off] : 0u);
        __syncthreads();
        unsigned* tmp = a; a = c; c = tmp;
    }
    // a = inclusive scan; exclusive = a[t]-hv
    if (t < BKT_SZ) {
        unsigned excl = a[t] - hv;
        cur[t] = excl;
        int n = n0 + t;
        if (n < n_nodes) {
            row_start[n] = base + excl;
            cnt[n] = hv;
            float di = rsqrtf((float)(hv + 1u));
            dinv[n] = di;
            unsigned w[5];
#pragma unroll
            for (int j = 0; j < 5; j++) {
                unsigned lo = __half_as_ushort(__float2half_rn(x[(size_t)n * 10 + 2 * j] * di));
                unsigned hi = __half_as_ushort(__float2half_rn(x[(size_t)n * 10 + 2 * j + 1] * di));
                w[j] = lo | (hi << 16);
            }
            char* row = xs + (size_t)n * XS_BYTES;
            *(uint4*)row = make_uint4(w[0], w[1], w[2], w[3]);
            *(uint2*)(row + 16) = make_uint2(w[4], 0u);
        }
    }
    __syncthreads();
    for (unsigned q = t; q < nquad; q += TPB_B) {
        uint4 w4 = B4[q];
        if (w4.x != SENTINEL) {
            unsigned pos = base + atomicAdd(&cur[w4.x >> DST_SHIFT], 1u);
            csr_src[pos] = w4.x & SRC_MASK;
        }
        if (w4.y != SENTINEL) {
            unsigned pos = base + atomicAdd(&cur[w4.y >> DST_SHIFT], 1u);
            csr_src[pos] = w4.y & SRC_MASK;
        }
        if (w4.z != SENTINEL) {
            unsigned pos = base + atomicAdd(&cur[w4.z >> DST_SHIFT], 1u);
            csr_src[pos] = w4.z & SRC_MASK;
        }
        if (w4.w != SENTINEL) {
            unsigned pos = base + atomicAdd(&cur[w4.w >> DST_SHIFT], 1u);
            csr_src[pos] = w4.w & SRC_MASK;
        }
    }
}

// Standalone node1 (fallback path only).
static __global__ void node1_kernel(const float* __restrict__ x, const float* __restrict__ dinv,
                                    char* __restrict__ xs, int n_nodes) {
    int i = blockIdx.x * blockDim.x + threadIdx.x;
    if (i >= n_nodes) return;
    float di = dinv[i];
    unsigned w[5];
#pragma unroll
    for (int j = 0; j < 5; j++) {
        unsigned lo = __half_as_ushort(__float2half_rn(x[(size_t)i * 10 + 2 * j] * di));
        unsigned hi = __half_as_ushort(__float2half_rn(x[(size_t)i * 10 + 2 * j + 1] * di));
        w[j] = lo | (hi << 16);
    }
    char* row = xs + (size_t)i * XS_BYTES;
    *(uint4*)row = make_uint4(w[0], w[1], w[2], w[3]);
    *(uint2*)(row + 16) = make_uint2(w[4], 0u);
}

// Layer-1 gather + dense 10->16->relu->2 fused. 16 lanes per node
// (4 nodes/wave): fp16 32B-row gathers (L2-resident table), fp32 accum.
static __global__ void gather1_kernel(const unsigned int* __restrict__ row_start,
                                      const unsigned int* __restrict__ cnt,
                                      const unsigned int* __restrict__ csr_src,
                                      const char* __restrict__ xs,
                                      const float* __restrict__ dinv,
                                      const float* __restrict__ W1, const float* __restrict__ b1,
                                      const float* __restrict__ W2,
                                      float* __restrict__ gs, int n_nodes) {
    __shared__ float sW1[160];
    __shared__ float sb1[16];
    __shared__ float sW2[32];
    for (int k = threadIdx.x; k < 160; k += blockDim.x) sW1[k] = W1[k];
    if (threadIdx.x < 16) sb1[threadIdx.x] = b1[threadIdx.x];
    if (threadIdx.x < 32) sW2[threadIdx.x] = W2[threadIdx.x];
    __syncthreads();
    int node = blockIdx.x * (blockDim.x >> 4) + (threadIdx.x >> 4);
    int lg = threadIdx.x & 15;
    if (node >= n_nodes) return;
    unsigned start = row_start[node];
    unsigned degn = cnt[node];
    float acc[10];
#pragma unroll
    for (int j = 0; j < 10; j++) acc[j] = 0.f;
    for (unsigned k = lg; k < degn; k += 16) {
        unsigned s = csr_src[start + k];
        const char* row = xs + (size_t)s * XS_BYTES;
        uint4 a = *(const uint4*)row;
        unsigned b = *(const unsigned*)(row + 16);
        float2 f;
        f = h2f(a.x); acc[0] += f.x; acc[1] += f.y;
        f = h2f(a.y); acc[2] += f.x; acc[3] += f.y;
        f = h2f(a.z); acc[4] += f.x; acc[5] += f.y;
        f = h2f(a.w); acc[6] += f.x; acc[7] += f.y;
        f = h2f(b);   acc[8] += f.x; acc[9] += f.y;
    }
    if (lg == 0) {   // self-loop contribution
        const char* row = xs + (size_t)node * XS_BYTES;
        uint4 a = *(const uint4*)row;
        unsigned b = *(const unsigned*)(row + 16);
        float2 f;
        f = h2f(a.x); acc[0] += f.x; acc[1] += f.y;
        f = h2f(a.y); acc[2] += f.x; acc[3] += f.y;
        f = h2f(a.z); acc[4] += f.x; acc[5] += f.y;
        f = h2f(a.w); acc[6] += f.x; acc[7] += f.y;
        f = h2f(b);   acc[8] += f.x; acc[9] += f.y;
    }
#pragma unroll
    for (int off = 8; off > 0; off >>= 1) {
#pragma unroll
        for (int j = 0; j < 10; j++) acc[j] += __shfl_xor(acc[j], off);
    }
    float di = dinv[node];
    float h = sb1[lg];
#pragma unroll
    for (int k = 0; k < 10; k++) h = fmaf(acc[k] * di, sW1[k * 16 + lg], h);
    h = fmaxf(h, 0.f);
    float g0 = h * sW2[lg * 2 + 0];
    float g1 = h * sW2[lg * 2 + 1];
#pragma unroll
    for (int off = 8; off > 0; off >>= 1) {
        g0 += __shfl_xor(g0, off);
        g1 += __shfl_xor(g1, off);
    }
    if (lg == 0) {
        float2 o;
        o.x = g0 * di;
        o.y = g1 * di;
        ((float2*)gs)[node] = o;
    }
}

// Layer-2 gather + final scale + bias. 16 lanes per node; gs/csr L2-warm.
static __global__ void gather2_kernel(const unsigned int* __restrict__ row_start,
                                      const unsigned int* __restrict__ cnt,
                                      const unsigned int* __restrict__ csr_src,
                                      const float* __restrict__ gs,
                                      const float* __restrict__ dinv,
                                      const float* __restrict__ b2,
                                      float* __restrict__ out, int n_nodes) {
    int node = blockIdx.x * (blockDim.x >> 4) + (threadIdx.x >> 4);
    int lg = threadIdx.x & 15;
    if (node >= n_nodes) return;
    unsigned start = row_start[node];
    unsigned degn = cnt[node];
    float a0 = 0.f, a1 = 0.f;
    const float2* G = (const float2*)gs;
    for (unsigned k = lg; k < degn; k += 16) {
        float2 v = G[csr_src[start + k]];
        a0 += v.x; a1 += v.y;
    }
    if (lg == 0) {   // self loop
        float2 s = G[node];
        a0 += s.x; a1 += s.y;
    }
#pragma unroll
    for (int off = 8; off > 0; off >>= 1) {
        a0 += __shfl_xor(a0, off);
        a1 += __shfl_xor(a1, off);
    }
    if (lg == 0) {
        float di = dinv[node];
        float2 o;
        o.x = fmaf(a0, di, b2[0]);
        o.y = fmaf(a1, di, b2[1]);
        ((float2*)out)[node] = o;
    }
}

// ---------------- fallback (atomic-CSR build) -------------------------------
static __global__ void deg_kernel(const void* __restrict__ ei, const int* __restrict__ flag,
                                  unsigned int* __restrict__ cnt, int n_edges) {
    const int is64 = *flag;
    unsigned stride = gridDim.x * blockDim.x;
    for (unsigned e = blockIdx.x * blockDim.x + threadIdx.x; e < (unsigned)n_edges; e += stride) {
        int d = nt_dst(ei, is64, n_edges, e);
        atomicAdd(&cnt[d], 1u);
    }
}
static __global__ void alloc_kernel(const unsigned int* __restrict__ cnt,
                                    unsigned int* __restrict__ row_start,
                                    unsigned int* __restrict__ cursor,
                                    unsigned int* __restrict__ gcur,
                                    float* __restrict__ dinv, int n_nodes) {
    __shared__ unsigned wsum[4];
    int i = blockIdx.x * blockDim.x + threadIdx.x;
    int lane = threadIdx.x & 63;
    int wid = threadIdx.x >> 6;
    unsigned d = (i < n_nodes) ? cnt[i] : 0u;
    unsigned scan = d;
#pragma unroll
    for (int off = 1; off < 64; off <<= 1) {
        unsigned t = __shfl_up(scan, off);
        if (lane >= off) scan += t;
    }
    if (lane == 63) wsum[wid] = scan;
    __syncthreads();
    if (threadIdx.x == 0) {
        unsigned s0 = wsum[0], s1 = wsum[1], s2 = wsum[2], s3 = wsum[3];
        unsigned base = atomicAdd(gcur, s0 + s1 + s2 + s3);
        wsum[0] = base;
        wsum[1] = base + s0;
        wsum[2] = base + s0 + s1;
        wsum[3] = base + s0 + s1 + s2;
    }
    __syncthreads();
    if (i < n_nodes) {
        unsigned pos = wsum[wid] + scan - d;
        row_start[i] = pos;
        cursor[i] = pos;
        dinv[i] = rsqrtf((float)(d + 1u));
    }
}
static __global__ void csrfill_kernel(const void* __restrict__ ei, const int* __restrict__ flag,
                                      unsigned int* __restrict__ cursor,
                                      unsigned int* __restrict__ csr_src, int n_edges) {
    const int is64 = *flag;
    unsigned stride = gridDim.x * blockDim.x;
    for (unsigned e = blockIdx.x * blockDim.x + threadIdx.x; e < (unsigned)n_edges; e += stride) {
        int s = nt_src(ei, is64, n_edges, e);
        int d = nt_dst(ei, is64, n_edges, e);
        unsigned pos = atomicAdd(&cursor[d], 1u);
        csr_src[pos] = (unsigned)s;
    }
}

static inline char* align_up(char* p, size_t a) {
    return (char*)(((uintptr_t)p + a - 1) & ~(uintptr_t)(a - 1));
}

extern "C" void kernel_launch(void* const* d_in, const int* in_sizes, int n_in,
                              void* d_out, int out_size, void* d_ws, size_t ws_size,
                              hipStream_t stream) {
    const float* x  = (const float*)d_in[0];
    const void*  ei = d_in[1];
    const float* W1 = (const float*)d_in[2];
    const float* b1 = (const float*)d_in[3];
    const float* W2 = (const float*)d_in[4];
    const float* b2 = (const float*)d_in[5];
    float* out = (float*)d_out;

    const int n_nodes = in_sizes[0] / 10;
    const int n_edges = in_sizes[1] / 2;
    (void)n_in; (void)out_size;

    const int nbuckets = (n_nodes + BKT_SZ - 1) >> BKT_BITS;
    const bool pack_ok = (n_nodes <= (1 << 17)) && (nbuckets <= NBK);
    // per-bucket region capacity: 1.25x mean + 2048, 16-aligned (~48 sigma slack)
    const unsigned cap = (unsigned)(((((size_t)n_edges / (size_t)(nbuckets > 0 ? nbuckets : 1)) * 5 / 4)
                                     + 2048 + 15) & ~(size_t)15);
    const size_t region_words = (size_t)nbuckets * cap + 64;

    char* p = (char*)d_ws;
    int* flag = (int*)p;
    unsigned* gcur = (unsigned*)(p + 64);
    p += 256;
    // common node buffers (each 256B-aligned)
    unsigned* row_start = (unsigned*)p; p = align_up(p + (size_t)n_nodes * 4, 256);
    unsigned* cnt = (unsigned*)p;       p = align_up(p + (size_t)n_nodes * 4, 256);
    float* dinv = (float*)p;            p = align_up(p + (size_t)n_nodes * 4, 256);
    float* gs = (float*)p;              p = align_up(p + (size_t)n_nodes * 8, 256);
    char* xs = p;                       p = align_up(p + (size_t)n_nodes * XS_BYTES, 256);

    const size_t head_bytes = (size_t)(p - (char*)d_ws);
    const size_t need_new = head_bytes + 2 * (region_words * 4 + 256) + NBK * 4 + 256;
    const size_t need_old = head_bytes + (size_t)n_edges * 4 + 256 +
                            (size_t)n_nodes * 4 + 256;

    const int NODES_PER_BLK = 256 / 16;  // 16-lane groups, 256-thread blocks
    const int gblocks = (n_nodes + NODES_PER_BLK - 1) / NODES_PER_BLK;

    if (pack_ok && ws_size >= need_new) {
        unsigned* csr_src = (unsigned*)p;  p = align_up(p + region_words * 4, 256);
        unsigned* gbase = (unsigned*)p;    p = align_up(p + (size_t)NBK * 4, 256);
        unsigned* bucketed = (unsigned*)p; p = align_up(p + region_words * 4, 256);

        const int nblocksB = (int)(((unsigned)n_edges + CHUNK - 1) / CHUNK);

        detect_init_kernel<<<1, 256, 0, stream>>>((const unsigned int*)ei, flag, gbase, cap);
        scatterB_kernel<<<nblocksB, TPB_A, 0, stream>>>(ei, flag, gbase, bucketed, n_edges, cap);
        passB_kernel<<<nbuckets, TPB_B, 0, stream>>>(bucketed, gbase, cap, x, csr_src,
                                                     row_start, cnt, dinv, xs, n_nodes);
        gather1_kernel<<<gblocks, 256, 0, stream>>>(row_start, cnt, csr_src, xs, dinv,
                                                    W1, b1, W2, gs, n_nodes);
        gather2_kernel<<<gblocks, 256, 0, stream>>>(row_start, cnt, csr_src, gs, dinv,
                                                    b2, out, n_nodes);
    } else if (ws_size >= need_old) {
        unsigned* csr_src = (unsigned*)p; p = align_up(p + (size_t)n_edges * 4, 256);
        unsigned* cursor = (unsigned*)p;

        hipMemsetAsync(d_ws, 0, 256, stream);
        hipMemsetAsync(cnt, 0, (size_t)n_nodes * 4, stream);
        detect_init_kernel<<<1, 256, 0, stream>>>((const unsigned int*)ei, flag, gcur, 0u);
        deg_kernel<<<2048, 256, 0, stream>>>(ei, flag, cnt, n_edges);
        alloc_kernel<<<(n_nodes + 255) / 256, 256, 0, stream>>>(cnt, row_start, cursor, gcur, dinv, n_nodes);
        csrfill_kernel<<<4096, 256, 0, stream>>>(ei, flag, cursor, csr_src, n_edges);
        node1_kernel<<<(n_nodes + 255) / 256, 256, 0, stream>>>(x, dinv, xs, n_nodes);
        gather1_kernel<<<gblocks, 256, 0, stream>>>(row_start, cnt, csr_src, xs, dinv,
                                                    W1, b1, W2, gs, n_nodes);
        gather2_kernel<<<gblocks, 256, 0, stream>>>(row_start, cnt, csr_src, gs, dinv,
                                                    b2, out, n_nodes);
    }
}

// Round 16
// 197.817 us; speedup vs baseline: 1.0105x; 1.0105x over previous
//
#include <hip/hip_runtime.h>
#include <hip/hip_fp16.h>

// ---------------------------------------------------------------------------
// 2-layer GCN: atomic-free CSR build (bucketed counting sort, 256-node
// buckets) + register-accumulating 16-lane-group gathers with fused dense.
//   out = dinv * (A (relu((dinv*(A' xs)) W1 + b1) W2 * dinv)) + b2
// xs = x*dinv stored FP16 in 32B rows (3.2MB, per-XCD-L2-resident gathers).
// (block,bucket) runs in `bucketed` are 64B-aligned (sentinel-padded) -> no
// cross-XCD false sharing. Measured geometry optimum (R11..R15): NBLKA=256,
// pair loads; R15's fused scatterB was net-neutral -> reverted (R14 base).
// NEW: gather loops manually unrolled (2x gather1, 4x gather2) so each lane
// keeps multiple independent row fetches in flight (dependent-chain fix).
// Edge packed: src | (local_dst << 24).
// ---------------------------------------------------------------------------

#define BKT_BITS  8
#define BKT_SZ    256       // nodes per bucket
#define NBK       512       // padded bucket slots (power of 2, >= n buckets)
#define NBLKA     256       // blocks in histA/scatterA (edge partition)
#define TPB_A     1024      // threads per block in histA/scatterA
#define TPB_B     1024      // threads per block in passB
#define DST_SHIFT 24
#define SRC_MASK  0xFFFFFFu
#define XS_BYTES  32        // bytes per xs row (10 fp16 + pad)
#define SENTINEL  0xFFFFFFFFu
#define PAD_ENTRIES ((size_t)NBLKA * NBK * 16)   // max alignment holes

static __device__ __forceinline__ int nt_src(const void* ei, int is64, int n_edges, unsigned e) {
    return is64 ? (int)__builtin_nontemporal_load(&((const long long*)ei)[e])
                : __builtin_nontemporal_load(&((const int*)ei)[e]);
}
static __device__ __forceinline__ int nt_dst(const void* ei, int is64, int n_edges, unsigned e) {
    return is64 ? (int)__builtin_nontemporal_load(&((const long long*)ei)[(unsigned)n_edges + e])
                : __builtin_nontemporal_load(&((const int*)ei)[(unsigned)n_edges + e]);
}
// Load edges e, e+1 of one half (0=src, 1=dst). Requires e even, n_edges even.
static __device__ __forceinline__ void load_pair(const void* ei, int is64, int n_edges,
                                                 unsigned e, int half,
                                                 unsigned& v0, unsigned& v1) {
    if (is64) {
        const unsigned long long* p =
            (const unsigned long long*)ei + (size_t)half * n_edges + e;
        unsigned long long a = __builtin_nontemporal_load(p);
        unsigned long long b = __builtin_nontemporal_load(p + 1);
        v0 = (unsigned)a; v1 = (unsigned)b;
    } else {
        const unsigned long long* p =
            (const unsigned long long*)((const int*)ei + (size_t)half * n_edges + e);
        unsigned long long a = __builtin_nontemporal_load(p);
        v0 = (unsigned)a; v1 = (unsigned)(a >> 32);
    }
}

static __device__ __forceinline__ float2 h2f(unsigned w) {
    __half2 h = *(__half2*)&w;
    return __half22float2(h);
}

// Detect whether edge_index arrived as int64 (odd 32-bit words all zero) or int32.
static __global__ void detect64_kernel(const unsigned int* __restrict__ w, int* flag) {
    __shared__ int nz;
    if (threadIdx.x == 0) nz = 0;
    __syncthreads();
    int local = 0;
    for (int k = threadIdx.x; k < 4096; k += blockDim.x)
        if (w[2 * k + 1] != 0u) local = 1;
    if (local) atomicOr(&nz, 1);
    __syncthreads();
    if (threadIdx.x == 0) *flag = (nz == 0) ? 1 : 0;  // 1 => int64 encoding
}

// Per-block LDS histogram over buckets (dst >> BKT_BITS). Paired loads.
static __global__ void histA_kernel(const void* __restrict__ ei, const int* __restrict__ flag,
                                    unsigned* __restrict__ histA, int n_edges) {
    __shared__ unsigned h[NBK];
    for (int i = threadIdx.x; i < NBK; i += TPB_A) h[i] = 0u;
    __syncthreads();
    const int is64 = *flag;
    unsigned gid = blockIdx.x * blockDim.x + threadIdx.x;
    if ((n_edges & 1) == 0) {
        unsigned stride2 = gridDim.x * blockDim.x * 2u;
        for (unsigned e = gid * 2u; e < (unsigned)n_edges; e += stride2) {
            unsigned d0, d1;
            load_pair(ei, is64, n_edges, e, 1, d0, d1);
            atomicAdd(&h[d0 >> BKT_BITS], 1u);
            atomicAdd(&h[d1 >> BKT_BITS], 1u);
        }
    } else {
        unsigned stride = gridDim.x * blockDim.x;
        for (unsigned e = gid; e < (unsigned)n_edges; e += stride) {
            int d = nt_dst(ei, is64, n_edges, e);
            atomicAdd(&h[(unsigned)d >> BKT_BITS], 1u);
        }
    }
    __syncthreads();
    for (int i = threadIdx.x; i < NBK; i += TPB_A)
        histA[blockIdx.x * NBK + i] = h[i];
}

// Per bucket slot b: exclusive scan of ALIGN16(histA[blk][b]) over blk.
// total[b] = padded bucket size (multiple of 16 edges = one 64B line).
static __global__ void scan1_kernel(unsigned* __restrict__ histA, unsigned* __restrict__ total) {
    __shared__ unsigned s0[NBLKA], s1[NBLKA];
    const int b = blockIdx.x;
    const int t = threadIdx.x;
    unsigned v = histA[t * NBK + b];
    unsigned va = (v + 15u) & ~15u;   // align run to 16 edges (64B)
    unsigned* a = s0; unsigned* c = s1;
    a[t] = va;
    __syncthreads();
    for (int off = 1; off < NBLKA; off <<= 1) {
        c[t] = a[t] + (t >= off ? a[t - off] : 0u);
        __syncthreads();
        unsigned* tmp = a; a = c; c = tmp;
    }
    histA[t * NBK + b] = a[t] - va;
    if (t == NBLKA - 1) total[b] = a[NBLKA - 1];
}

// Exclusive scan of (padded) bucket totals -> bucket_base.
static __global__ void scan2_kernel(const unsigned* __restrict__ total,
                                    unsigned* __restrict__ bucket_base) {
    __shared__ unsigned s0[NBK], s1[NBK];
    const int t = threadIdx.x;
    unsigned v = total[t];
    unsigned* a = s0; unsigned* c = s1;
    a[t] = v;
    __syncthreads();
    for (int off = 1; off < NBK; off <<= 1) {
        c[t] = a[t] + (t >= off ? a[t - off] : 0u);
        __syncthreads();
        unsigned* tmp = a; a = c; c = tmp;
    }
    bucket_base[t] = a[t] - v;
}

// Scatter edges into dst-bucketed order, packed: src | (local_dst << 24).
// Runs are 64B-aligned; tails padded with SENTINEL (same-line stores).
static __global__ void scatterA_kernel(const void* __restrict__ ei, const int* __restrict__ flag,
                                       const unsigned* __restrict__ histA,
                                       const unsigned* __restrict__ bucket_base,
                                       unsigned* __restrict__ bucketed, int n_edges) {
    __shared__ unsigned cur[NBK];
    __shared__ unsigned rstart[NBK];
    for (int i = threadIdx.x; i < NBK; i += TPB_A) {
        unsigned st = bucket_base[i] + histA[blockIdx.x * NBK + i];
        rstart[i] = st;
        cur[i] = st;
    }
    __syncthreads();
    const int is64 = *flag;
    unsigned gid = blockIdx.x * blockDim.x + threadIdx.x;
    if ((n_edges & 1) == 0) {
        unsigned stride2 = gridDim.x * blockDim.x * 2u;
        for (unsigned e = gid * 2u; e < (unsigned)n_edges; e += stride2) {
            unsigned s0, s1, d0, d1;
            load_pair(ei, is64, n_edges, e, 0, s0, s1);
            load_pair(ei, is64, n_edges, e, 1, d0, d1);
            unsigned p0 = atomicAdd(&cur[d0 >> BKT_BITS], 1u);
            unsigned p1 = atomicAdd(&cur[d1 >> BKT_BITS], 1u);
            bucketed[p0] = s0 | ((d0 & (BKT_SZ - 1u)) << DST_SHIFT);
            bucketed[p1] = s1 | ((d1 & (BKT_SZ - 1u)) << DST_SHIFT);
        }
    } else {
        unsigned stride = gridDim.x * blockDim.x;
        for (unsigned e = gid; e < (unsigned)n_edges; e += stride) {
            unsigned s = (unsigned)nt_src(ei, is64, n_edges, e);
            unsigned d = (unsigned)nt_dst(ei, is64, n_edges, e);
            unsigned pos = atomicAdd(&cur[d >> BKT_BITS], 1u);
            bucketed[pos] = s | ((d & (BKT_SZ - 1u)) << DST_SHIFT);
        }
    }
    __syncthreads();
    // pad each of this block's run tails to the 16-edge boundary
    for (int i = threadIdx.x; i < NBK; i += TPB_A) {
        unsigned st = rstart[i];
        unsigned cu = cur[i];
        unsigned end = st + ((cu - st + 15u) & ~15u);
        for (unsigned q = cu; q < end; ++q) bucketed[q] = SENTINEL;
    }
}

// Per 256-node bucket: counting sort by local dst (skipping sentinels); emit
// csr_src, row_start, cnt, dinv AND xs = fp16(x*dinv). 1024 threads; 4-way
// split LDS histogram. Both passes over `bucketed` use uint4 loads (runs are
// 16-word padded: base%16==0, count%16==0 -> no tail handling needed).
static __global__ void passB_kernel(const unsigned* __restrict__ bucketed,
                                    const unsigned* __restrict__ total,
                                    const unsigned* __restrict__ bucket_base,
                                    const float* __restrict__ x,
                                    unsigned* __restrict__ csr_src,
                                    unsigned* __restrict__ row_start,
                                    unsigned* __restrict__ cnt,
                                    float* __restrict__ dinv,
                                    char* __restrict__ xs, int n_nodes) {
    const int b = blockIdx.x;
    const int n0 = b << BKT_BITS;
    const int t = threadIdx.x;
    const unsigned base = bucket_base[b];
    const unsigned count = total[b];   // padded count (multiple of 16)

    __shared__ unsigned h4[4][BKT_SZ];
    __shared__ unsigned s0[BKT_SZ], s1[BKT_SZ];
    __shared__ unsigned cur[BKT_SZ];
    for (int i = t; i < 4 * BKT_SZ; i += TPB_B) ((unsigned*)h4)[i] = 0u;
    __syncthreads();
    const int copy = (t >> 8) & 3;
    const uint4* B4 = (const uint4*)(bucketed + base);
    const unsigned nquad = count >> 2;
    for (unsigned q = t; q < nquad; q += TPB_B) {
        uint4 w4 = B4[q];
        if (w4.x != SENTINEL) atomicAdd(&h4[copy][w4.x >> DST_SHIFT], 1u);
        if (w4.y != SENTINEL) atomicAdd(&h4[copy][w4.y >> DST_SHIFT], 1u);
        if (w4.z != SENTINEL) atomicAdd(&h4[copy][w4.z >> DST_SHIFT], 1u);
        if (w4.w != SENTINEL) atomicAdd(&h4[copy][w4.w >> DST_SHIFT], 1u);
    }
    __syncthreads();
    unsigned hv = 0;
    unsigned* a = s0; unsigned* c = s1;
    if (t < BKT_SZ) {
        hv = h4[0][t] + h4[1][t] + h4[2][t] + h4[3][t];
        a[t] = hv;
    }
    __syncthreads();
    for (int off = 1; off < BKT_SZ; off <<= 1) {
        if (t < BKT_SZ) c[t] = a[t] + (t >= off ? a[t - off] : 0u);
        __syncthreads();
        unsigned* tmp = a; a = c; c = tmp;
    }
    // a = inclusive scan; exclusive = a[t]-hv
    if (t < BKT_SZ) {
        unsigned excl = a[t] - hv;
        cur[t] = excl;
        int n = n0 + t;
        if (n < n_nodes) {
            row_start[n] = base + excl;
            cnt[n] = hv;
            float di = rsqrtf((float)(hv + 1u));
            dinv[n] = di;
            unsigned w[5];
#pragma unroll
            for (int j = 0; j < 5; j++) {
                unsigned lo = __half_as_ushort(__float2half_rn(x[(size_t)n * 10 + 2 * j] * di));
                unsigned hi = __half_as_ushort(__float2half_rn(x[(size_t)n * 10 + 2 * j + 1] * di));
                w[j] = lo | (hi << 16);
            }
            char* row = xs + (size_t)n * XS_BYTES;
            *(uint4*)row = make_uint4(w[0], w[1], w[2], w[3]);
            *(uint2*)(row + 16) = make_uint2(w[4], 0u);
        }
    }
    __syncthreads();
    for (unsigned q = t; q < nquad; q += TPB_B) {
        uint4 w4 = B4[q];
        if (w4.x != SENTINEL) {
            unsigned pos = base + atomicAdd(&cur[w4.x >> DST_SHIFT], 1u);
            csr_src[pos] = w4.x & SRC_MASK;
        }
        if (w4.y != SENTINEL) {
            unsigned pos = base + atomicAdd(&cur[w4.y >> DST_SHIFT], 1u);
            csr_src[pos] = w4.y & SRC_MASK;
        }
        if (w4.z != SENTINEL) {
            unsigned pos = base + atomicAdd(&cur[w4.z >> DST_SHIFT], 1u);
            csr_src[pos] = w4.z & SRC_MASK;
        }
        if (w4.w != SENTINEL) {
            unsigned pos = base + atomicAdd(&cur[w4.w >> DST_SHIFT], 1u);
            csr_src[pos] = w4.w & SRC_MASK;
        }
    }
}

// Standalone node1 (fallback path only).
static __global__ void node1_kernel(const float* __restrict__ x, const float* __restrict__ dinv,
                                    char* __restrict__ xs, int n_nodes) {
    int i = blockIdx.x * blockDim.x + threadIdx.x;
    if (i >= n_nodes) return;
    float di = dinv[i];
    unsigned w[5];
#pragma unroll
    for (int j = 0; j < 5; j++) {
        unsigned lo = __half_as_ushort(__float2half_rn(x[(size_t)i * 10 + 2 * j] * di));
        unsigned hi = __half_as_ushort(__float2half_rn(x[(size_t)i * 10 + 2 * j + 1] * di));
        w[j] = lo | (hi << 16);
    }
    char* row = xs + (size_t)i * XS_BYTES;
    *(uint4*)row = make_uint4(w[0], w[1], w[2], w[3]);
    *(uint2*)(row + 16) = make_uint2(w[4], 0u);
}

// Layer-1 gather + dense 10->16->relu->2 fused. 16 lanes per node
// (4 nodes/wave): fp16 32B-row gathers (L2-resident table), fp32 accum.
// Unrolled 2x: two independent row fetches in flight per lane.
static __global__ void gather1_kernel(const unsigned int* __restrict__ row_start,
                                      const unsigned int* __restrict__ cnt,
                                      const unsigned int* __restrict__ csr_src,
                                      const char* __restrict__ xs,
                                      const float* __restrict__ dinv,
                                      const float* __restrict__ W1, const float* __restrict__ b1,
                                      const float* __restrict__ W2,
                                      float* __restrict__ gs, int n_nodes) {
    __shared__ float sW1[160];
    __shared__ float sb1[16];
    __shared__ float sW2[32];
    for (int k = threadIdx.x; k < 160; k += blockDim.x) sW1[k] = W1[k];
    if (threadIdx.x < 16) sb1[threadIdx.x] = b1[threadIdx.x];
    if (threadIdx.x < 32) sW2[threadIdx.x] = W2[threadIdx.x];
    __syncthreads();
    int node = blockIdx.x * (blockDim.x >> 4) + (threadIdx.x >> 4);
    int lg = threadIdx.x & 15;
    if (node >= n_nodes) return;
    unsigned start = row_start[node];
    unsigned degn = cnt[node];
    float acc[10];
#pragma unroll
    for (int j = 0; j < 10; j++) acc[j] = 0.f;
    for (unsigned k = lg; k < degn; k += 32) {
        unsigned s0 = csr_src[start + k];
        unsigned k1 = k + 16;
        bool v1 = k1 < degn;
        unsigned s1 = v1 ? csr_src[start + k1] : s0;
        const char* r0 = xs + (size_t)s0 * XS_BYTES;
        const char* r1 = xs + (size_t)s1 * XS_BYTES;
        uint4 a0 = *(const uint4*)r0;
        unsigned b0 = *(const unsigned*)(r0 + 16);
        uint4 a1 = *(const uint4*)r1;
        unsigned b1w = *(const unsigned*)(r1 + 16);
        float2 f;
        f = h2f(a0.x); acc[0] += f.x; acc[1] += f.y;
        f = h2f(a0.y); acc[2] += f.x; acc[3] += f.y;
        f = h2f(a0.z); acc[4] += f.x; acc[5] += f.y;
        f = h2f(a0.w); acc[6] += f.x; acc[7] += f.y;
        f = h2f(b0);   acc[8] += f.x; acc[9] += f.y;
        if (v1) {
            f = h2f(a1.x); acc[0] += f.x; acc[1] += f.y;
            f = h2f(a1.y); acc[2] += f.x; acc[3] += f.y;
            f = h2f(a1.z); acc[4] += f.x; acc[5] += f.y;
            f = h2f(a1.w); acc[6] += f.x; acc[7] += f.y;
            f = h2f(b1w);  acc[8] += f.x; acc[9] += f.y;
        }
    }
    if (lg == 0) {   // self-loop contribution
        const char* row = xs + (size_t)node * XS_BYTES;
        uint4 a = *(const uint4*)row;
        unsigned b = *(const unsigned*)(row + 16);
        float2 f;
        f = h2f(a.x); acc[0] += f.x; acc[1] += f.y;
        f = h2f(a.y); acc[2] += f.x; acc[3] += f.y;
        f = h2f(a.z); acc[4] += f.x; acc[5] += f.y;
        f = h2f(a.w); acc[6] += f.x; acc[7] += f.y;
        f = h2f(b);   acc[8] += f.x; acc[9] += f.y;
    }
#pragma unroll
    for (int off = 8; off > 0; off >>= 1) {
#pragma unroll
        for (int j = 0; j < 10; j++) acc[j] += __shfl_xor(acc[j], off);
    }
    float di = dinv[node];
    float h = sb1[lg];
#pragma unroll
    for (int k = 0; k < 10; k++) h = fmaf(acc[k] * di, sW1[k * 16 + lg], h);
    h = fmaxf(h, 0.f);
    float g0 = h * sW2[lg * 2 + 0];
    float g1 = h * sW2[lg * 2 + 1];
#pragma unroll
    for (int off = 8; off > 0; off >>= 1) {
        g0 += __shfl_xor(g0, off);
        g1 += __shfl_xor(g1, off);
    }
    if (lg == 0) {
        float2 o;
        o.x = g0 * di;
        o.y = g1 * di;
        ((float2*)gs)[node] = o;
    }
}

// Layer-2 gather + final scale + bias. 16 lanes per node; gs/csr L2-warm.
// Unrolled 4x: four independent 8B fetches in flight per lane.
static __global__ void gather2_kernel(const unsigned int* __restrict__ row_start,
                                      const unsigned int* __restrict__ cnt,
                                      const unsigned int* __restrict__ csr_src,
                                      const float* __restrict__ gs,
                                      const float* __restrict__ dinv,
                                      const float* __restrict__ b2,
                                      float* __restrict__ out, int n_nodes) {
    int node = blockIdx.x * (blockDim.x >> 4) + (threadIdx.x >> 4);
    int lg = threadIdx.x & 15;
    if (node >= n_nodes) return;
    unsigned start = row_start[node];
    unsigned degn = cnt[node];
    float a0 = 0.f, a1 = 0.f;
    const float2* G = (const float2*)gs;
    for (unsigned k = lg; k < degn; k += 64) {
        unsigned k1 = k + 16, k2 = k + 32, k3 = k + 48;
        bool v1 = k1 < degn, v2 = k2 < degn, v3 = k3 < degn;
        unsigned s0 = csr_src[start + k];
        unsigned s1 = v1 ? csr_src[start + k1] : s0;
        unsigned s2 = v2 ? csr_src[start + k2] : s0;
        unsigned s3 = v3 ? csr_src[start + k3] : s0;
        float2 w0 = G[s0];
        float2 w1 = G[s1];
        float2 w2 = G[s2];
        float2 w3 = G[s3];
        a0 += w0.x; a1 += w0.y;
        if (v1) { a0 += w1.x; a1 += w1.y; }
        if (v2) { a0 += w2.x; a1 += w2.y; }
        if (v3) { a0 += w3.x; a1 += w3.y; }
    }
    if (lg == 0) {   // self loop
        float2 s = G[node];
        a0 += s.x; a1 += s.y;
    }
#pragma unroll
    for (int off = 8; off > 0; off >>= 1) {
        a0 += __shfl_xor(a0, off);
        a1 += __shfl_xor(a1, off);
    }
    if (lg == 0) {
        float di = dinv[node];
        float2 o;
        o.x = fmaf(a0, di, b2[0]);
        o.y = fmaf(a1, di, b2[1]);
        ((float2*)out)[node] = o;
    }
}

// ---------------- fallback (atomic-CSR build) -------------------------------
static __global__ void deg_kernel(const void* __restrict__ ei, const int* __restrict__ flag,
                                  unsigned int* __restrict__ cnt, int n_edges) {
    const int is64 = *flag;
    unsigned stride = gridDim.x * blockDim.x;
    for (unsigned e = blockIdx.x * blockDim.x + threadIdx.x; e < (unsigned)n_edges; e += stride) {
        int d = nt_dst(ei, is64, n_edges, e);
        atomicAdd(&cnt[d], 1u);
    }
}
static __global__ void alloc_kernel(const unsigned int* __restrict__ cnt,
                                    unsigned int* __restrict__ row_start,
                                    unsigned int* __restrict__ cursor,
                                    unsigned int* __restrict__ gcur,
                                    float* __restrict__ dinv, int n_nodes) {
    __shared__ unsigned wsum[4];
    int i = blockIdx.x * blockDim.x + threadIdx.x;
    int lane = threadIdx.x & 63;
    int wid = threadIdx.x >> 6;
    unsigned d = (i < n_nodes) ? cnt[i] : 0u;
    unsigned scan = d;
#pragma unroll
    for (int off = 1; off < 64; off <<= 1) {
        unsigned t = __shfl_up(scan, off);
        if (lane >= off) scan += t;
    }
    if (lane == 63) wsum[wid] = scan;
    __syncthreads();
    if (threadIdx.x == 0) {
        unsigned s0 = wsum[0], s1 = wsum[1], s2 = wsum[2], s3 = wsum[3];
        unsigned base = atomicAdd(gcur, s0 + s1 + s2 + s3);
        wsum[0] = base;
        wsum[1] = base + s0;
        wsum[2] = base + s0 + s1;
        wsum[3] = base + s0 + s1 + s2;
    }
    __syncthreads();
    if (i < n_nodes) {
        unsigned pos = wsum[wid] + scan - d;
        row_start[i] = pos;
        cursor[i] = pos;
        dinv[i] = rsqrtf((float)(d + 1u));
    }
}
static __global__ void csrfill_kernel(const void* __restrict__ ei, const int* __restrict__ flag,
                                      unsigned int* __restrict__ cursor,
                                      unsigned int* __restrict__ csr_src, int n_edges) {
    const int is64 = *flag;
    unsigned stride = gridDim.x * blockDim.x;
    for (unsigned e = blockIdx.x * blockDim.x + threadIdx.x; e < (unsigned)n_edges; e += stride) {
        int s = nt_src(ei, is64, n_edges, e);
        int d = nt_dst(ei, is64, n_edges, e);
        unsigned pos = atomicAdd(&cursor[d], 1u);
        csr_src[pos] = (unsigned)s;
    }
}

static inline char* align_up(char* p, size_t a) {
    return (char*)(((uintptr_t)p + a - 1) & ~(uintptr_t)(a - 1));
}

extern "C" void kernel_launch(void* const* d_in, const int* in_sizes, int n_in,
                              void* d_out, int out_size, void* d_ws, size_t ws_size,
                              hipStream_t stream) {
    const float* x  = (const float*)d_in[0];
    const void*  ei = d_in[1];
    const float* W1 = (const float*)d_in[2];
    const float* b1 = (const float*)d_in[3];
    const float* W2 = (const float*)d_in[4];
    const float* b2 = (const float*)d_in[5];
    float* out = (float*)d_out;

    const int n_nodes = in_sizes[0] / 10;
    const int n_edges = in_sizes[1] / 2;
    (void)n_in; (void)out_size;

    const int nbuckets = (n_nodes + BKT_SZ - 1) >> BKT_BITS;
    const bool pack_ok = (n_nodes <= (1 << DST_SHIFT)) && (nbuckets <= NBK);
    const size_t padded_edges = (size_t)n_edges + PAD_ENTRIES;

    char* p = (char*)d_ws;
    int* flag = (int*)p;
    unsigned* gcur = (unsigned*)(p + 64);
    p += 256;
    // common node buffers (each 256B-aligned)
    unsigned* row_start = (unsigned*)p; p = align_up(p + (size_t)n_nodes * 4, 256);
    unsigned* cnt = (unsigned*)p;       p = align_up(p + (size_t)n_nodes * 4, 256);
    float* dinv = (float*)p;            p = align_up(p + (size_t)n_nodes * 4, 256);
    float* gs = (float*)p;              p = align_up(p + (size_t)n_nodes * 8, 256);
    char* xs = p;                       p = align_up(p + (size_t)n_nodes * XS_BYTES, 256);

    const size_t head_bytes = (size_t)(p - (char*)d_ws);
    const size_t need_new = head_bytes + padded_edges * 4 /*csr*/ + 256 +
                            (size_t)NBLKA * NBK * 4 + 2 * (size_t)NBK * 4 + 1024 +
                            padded_edges * 4 /*bucketed*/ + 256;
    const size_t need_old = head_bytes + (size_t)n_edges * 4 + 256 +
                            (size_t)n_nodes * 4 + 256;

    const int NODES_PER_BLK = 256 / 16;  // 16-lane groups, 256-thread blocks
    const int gblocks = (n_nodes + NODES_PER_BLK - 1) / NODES_PER_BLK;

    if (pack_ok && ws_size >= need_new) {
        unsigned* csr_src = (unsigned*)p;     p = align_up(p + padded_edges * 4, 256);
        unsigned* histA = (unsigned*)p;       p = align_up(p + (size_t)NBLKA * NBK * 4, 256);
        unsigned* total = (unsigned*)p;       p = align_up(p + (size_t)NBK * 4, 256);
        unsigned* bucket_base = (unsigned*)p; p = align_up(p + (size_t)NBK * 4, 256);
        unsigned* bucketed = (unsigned*)p;    p = align_up(p + padded_edges * 4, 256);

        detect64_kernel<<<1, 256, 0, stream>>>((const unsigned int*)ei, flag);
        histA_kernel<<<NBLKA, TPB_A, 0, stream>>>(ei, flag, histA, n_edges);
        scan1_kernel<<<NBK, NBLKA, 0, stream>>>(histA, total);
        scan2_kernel<<<1, NBK, 0, stream>>>(total, bucket_base);
        scatterA_kernel<<<NBLKA, TPB_A, 0, stream>>>(ei, flag, histA, bucket_base, bucketed, n_edges);
        passB_kernel<<<nbuckets, TPB_B, 0, stream>>>(bucketed, total, bucket_base, x, csr_src,
                                                     row_start, cnt, dinv, xs, n_nodes);
        gather1_kernel<<<gblocks, 256, 0, stream>>>(row_start, cnt, csr_src, xs, dinv,
                                                    W1, b1, W2, gs, n_nodes);
        gather2_kernel<<<gblocks, 256, 0, stream>>>(row_start, cnt, csr_src, gs, dinv,
                                                    b2, out, n_nodes);
    } else if (ws_size >= need_old) {
        unsigned* csr_src = (unsigned*)p; p = align_up(p + (size_t)n_edges * 4, 256);
        unsigned* cursor = (unsigned*)p;

        hipMemsetAsync(d_ws, 0, 256, stream);
        hipMemsetAsync(cnt, 0, (size_t)n_nodes * 4, stream);
        detect64_kernel<<<1, 256, 0, stream>>>((const unsigned int*)ei, flag);
        deg_kernel<<<2048, 256, 0, stream>>>(ei, flag, cnt, n_edges);
        alloc_kernel<<<(n_nodes + 255) / 256, 256, 0, stream>>>(cnt, row_start, cursor, gcur, dinv, n_nodes);
        csrfill_kernel<<<4096, 256, 0, stream>>>(ei, flag, cursor, csr_src, n_edges);
        node1_kernel<<<(n_nodes + 255) / 256, 256, 0, stream>>>(x, dinv, xs, n_nodes);
        gather1_kernel<<<gblocks, 256, 0, stream>>>(row_start, cnt, csr_src, xs, dinv,
                                                    W1, b1, W2, gs, n_nodes);
        gather2_kernel<<<gblocks, 256, 0, stream>>>(row_start, cnt, csr_src, gs, dinv,
                                                    b2, out, n_nodes);
    }
}

// Round 17
// 196.832 us; speedup vs baseline: 1.0156x; 1.0050x over previous
//
#include <hip/hip_runtime.h>
#include <hip/hip_fp16.h>

// ---------------------------------------------------------------------------
// 2-layer GCN: fused atomic-claim CSR build + 16-lane-group gathers.
//   out = dinv * (A (relu((dinv*(A' xs)) W1 + b1) W2 * dinv)) + b2
// LLC-BW model (R11..R16): build kernels all stream at ~2 TB/s effective ->
// optimize BYTES, not parallelism. scatterB reads the edge list exactly once
// (dst cached in LDS: u16 low bits + ballot bit-16 bitmap; n_nodes < 2^17),
// claims 64B-aligned runs via global atomicAdd on fixed-cap bucket regions
// (no cross-XCD false sharing). passB caches the first 56KB of each bucket
// in LDS so the placement pass re-reads only the tail.
// xs = x*dinv stored FP16 in 32B rows (3.2MB, per-XCD-L2-resident gathers).
// Edge packed: src | (local_dst << 24).
// ---------------------------------------------------------------------------

#define BKT_BITS  8
#define BKT_SZ    256       // nodes per bucket
#define NBK       512       // padded bucket slots (>= n buckets)
#define TPB_A     1024      // threads per block in scatterB
#define TPB_B     1024      // threads per block in passB
#define CHUNK     25600     // edges per scatterB block (25 x 1024)
#define NIT       (CHUNK / TPB_A)
#define DST_SHIFT 24
#define SRC_MASK  0xFFFFFFu
#define XS_BYTES  32        // bytes per xs row (10 fp16 + pad)
#define SENTINEL  0xFFFFFFFFu
#define CACHE_W   14336     // passB LDS cache words (56 KB)

static __device__ __forceinline__ int nt_src(const void* ei, int is64, int n_edges, unsigned e) {
    return is64 ? (int)__builtin_nontemporal_load(&((const long long*)ei)[e])
                : __builtin_nontemporal_load(&((const int*)ei)[e]);
}
static __device__ __forceinline__ int nt_dst(const void* ei, int is64, int n_edges, unsigned e) {
    return is64 ? (int)__builtin_nontemporal_load(&((const long long*)ei)[(unsigned)n_edges + e])
                : __builtin_nontemporal_load(&((const int*)ei)[(unsigned)n_edges + e]);
}

static __device__ __forceinline__ float2 h2f(unsigned w) {
    __half2 h = *(__half2*)&w;
    return __half22float2(h);
}

// Detect int64 vs int32 edge encoding; init per-bucket claim cursors.
static __global__ void detect_init_kernel(const unsigned int* __restrict__ w, int* flag,
                                          unsigned* __restrict__ gbase, unsigned cap) {
    __shared__ int nz;
    if (threadIdx.x == 0) nz = 0;
    __syncthreads();
    int local = 0;
    for (int k = threadIdx.x; k < 4096; k += blockDim.x)
        if (w[2 * k + 1] != 0u) local = 1;
    if (local) atomicOr(&nz, 1);
    __syncthreads();
    if (threadIdx.x == 0) *flag = (nz == 0) ? 1 : 0;  // 1 => int64 encoding
    for (int b = threadIdx.x; b < NBK; b += blockDim.x)
        gbase[b] = (unsigned)b * cap;
}

// Fused hist + claim + scatter. One contiguous CHUNK of edges per block.
static __global__ void scatterB_kernel(const void* __restrict__ ei, const int* __restrict__ flag,
                                       unsigned* __restrict__ gbase,
                                       unsigned* __restrict__ bucketed,
                                       int n_edges, unsigned cap) {
    __shared__ unsigned short dlo[CHUNK];       // dst low 16 bits
    __shared__ unsigned dbit[CHUNK / 32];       // dst bit 16 (n_nodes < 2^17)
    __shared__ unsigned h[NBK];
    __shared__ unsigned runbase[NBK];
    __shared__ unsigned cur[NBK];
    const int t = threadIdx.x;
    const unsigned e0 = (unsigned)blockIdx.x * CHUNK;
    const int is64 = *flag;
    for (int i = t; i < NBK; i += TPB_A) h[i] = 0u;
    __syncthreads();
    // subpass 1: read dst once, cache in LDS, histogram
    for (int it = 0; it < NIT; ++it) {
        unsigned idx = (unsigned)it * TPB_A + (unsigned)t;
        unsigned e = e0 + idx;
        bool valid = e < (unsigned)n_edges;
        unsigned d = valid ? (unsigned)nt_dst(ei, is64, n_edges, e) : 0u;
        dlo[idx] = (unsigned short)d;
        unsigned long long m = __ballot((d >> 16) & 1u);
        if ((t & 31) == 0)
            dbit[idx >> 5] = (unsigned)(((t & 63) >= 32) ? (m >> 32) : m);
        if (valid) atomicAdd(&h[d >> BKT_BITS], 1u);
    }
    __syncthreads();
    // claim 64B-aligned space per (block,bucket) run
    for (int b = t; b < NBK; b += TPB_A) {
        unsigned hb = h[b];
        unsigned rb = 0u;
        if (hb) rb = atomicAdd(&gbase[b], (hb + 15u) & ~15u);
        runbase[b] = rb;
        cur[b] = rb;
    }
    __syncthreads();
    // subpass 2: read src only; reconstruct dst from LDS; scatter
    for (int it = 0; it < NIT; ++it) {
        unsigned idx = (unsigned)it * TPB_A + (unsigned)t;
        unsigned e = e0 + idx;
        if (e < (unsigned)n_edges) {
            unsigned s = (unsigned)nt_src(ei, is64, n_edges, e);
            unsigned d = (unsigned)dlo[idx] | (((dbit[idx >> 5] >> (idx & 31u)) & 1u) << 16);
            unsigned b = d >> BKT_BITS;
            unsigned pos = atomicAdd(&cur[b], 1u);
            if (pos < (b + 1u) * cap)   // overflow clamp (~48 sigma, never in practice)
                bucketed[pos] = s | ((d & (BKT_SZ - 1u)) << DST_SHIFT);
        }
    }
    __syncthreads();
    // pad run tails to the 16-edge (64B) boundary with sentinels
    for (int b = t; b < NBK; b += TPB_A) {
        if (!h[b]) continue;
        unsigned rb = runbase[b];
        unsigned lim = (b + 1u) * cap;
        unsigned cu = cur[b]; if (cu > lim) cu = lim;
        unsigned end = rb + ((cu - rb + 15u) & ~15u);
        if (end > lim) end = lim;
        for (unsigned q = cu; q < end; ++q) bucketed[q] = SENTINEL;
    }
}

// Per 256-node bucket: counting sort by local dst (skipping sentinels); emit
// csr_src, row_start, cnt, dinv AND xs = fp16(x*dinv). First CACHE_W words of
// the bucket are cached in LDS during the histogram pass so the placement
// pass re-reads only the tail from L3. uint4 accesses (runs 16-word padded).
static __global__ void passB_kernel(const unsigned* __restrict__ bucketed,
                                    const unsigned* __restrict__ gbase, unsigned cap,
                                    const float* __restrict__ x,
                                    unsigned* __restrict__ csr_src,
                                    unsigned* __restrict__ row_start,
                                    unsigned* __restrict__ cnt,
                                    float* __restrict__ dinv,
                                    char* __restrict__ xs, int n_nodes) {
    const int b = blockIdx.x;
    const int n0 = b << BKT_BITS;
    const int t = threadIdx.x;
    const unsigned base = (unsigned)b * cap;
    unsigned gb = gbase[b];
    unsigned lim = base + cap;
    if (gb > lim) gb = lim;
    const unsigned count = gb - base;   // padded count (multiple of 16)

    __shared__ unsigned cacheW[CACHE_W];        // 56 KB bucket cache
    __shared__ unsigned h2[2][BKT_SZ];
    __shared__ unsigned s0[BKT_SZ], s1[BKT_SZ];
    __shared__ unsigned cur[BKT_SZ];
    for (int i = t; i < 2 * BKT_SZ; i += TPB_B) ((unsigned*)h2)[i] = 0u;
    __syncthreads();
    const int copy = (t >> 9) & 1;
    const uint4* B4 = (const uint4*)(bucketed + base);
    uint4* C4 = (uint4*)cacheW;
    const unsigned nquad = count >> 2;
    const unsigned cquad = CACHE_W >> 2;
    for (unsigned q = t; q < nquad; q += TPB_B) {
        uint4 w4 = B4[q];
        if (q < cquad) C4[q] = w4;
        if (w4.x != SENTINEL) atomicAdd(&h2[copy][w4.x >> DST_SHIFT], 1u);
        if (w4.y != SENTINEL) atomicAdd(&h2[copy][w4.y >> DST_SHIFT], 1u);
        if (w4.z != SENTINEL) atomicAdd(&h2[copy][w4.z >> DST_SHIFT], 1u);
        if (w4.w != SENTINEL) atomicAdd(&h2[copy][w4.w >> DST_SHIFT], 1u);
    }
    __syncthreads();
    unsigned hv = 0;
    unsigned* a = s0; unsigned* c = s1;
    if (t < BKT_SZ) {
        hv = h2[0][t] + h2[1][t];
        a[t] = hv;
    }
    __syncthreads();
    for (int off = 1; off < BKT_SZ; off <<= 1) {
        if (t < BKT_SZ) c[t] = a[t] + (t >= off ? a[t - off] : 0u);
        __syncthreads();
        unsigned* tmp = a; a = c; c = tmp;
    }
    // a = inclusive scan; exclusive = a[t]-hv
    if (t < BKT_SZ) {
        unsigned excl = a[t] - hv;
        cur[t] = excl;
        int n = n0 + t;
        if (n < n_nodes) {
            row_start[n] = base + excl;
            cnt[n] = hv;
            float di = rsqrtf((float)(hv + 1u));
            dinv[n] = di;
            unsigned w[5];
#pragma unroll
            for (int j = 0; j < 5; j++) {
                unsigned lo = __half_as_ushort(__float2half_rn(x[(size_t)n * 10 + 2 * j] * di));
                unsigned hi = __half_as_ushort(__float2half_rn(x[(size_t)n * 10 + 2 * j + 1] * di));
                w[j] = lo | (hi << 16);
            }
            char* row = xs + (size_t)n * XS_BYTES;
            *(uint4*)row = make_uint4(w[0], w[1], w[2], w[3]);
            *(uint2*)(row + 16) = make_uint2(w[4], 0u);
        }
    }
    __syncthreads();
    for (unsigned q = t; q < nquad; q += TPB_B) {
        uint4 w4 = (q < cquad) ? C4[q] : B4[q];
        if (w4.x != SENTINEL) {
            unsigned pos = base + atomicAdd(&cur[w4.x >> DST_SHIFT], 1u);
            csr_src[pos] = w4.x & SRC_MASK;
        }
        if (w4.y != SENTINEL) {
            unsigned pos = base + atomicAdd(&cur[w4.y >> DST_SHIFT], 1u);
            csr_src[pos] = w4.y & SRC_MASK;
        }
        if (w4.z != SENTINEL) {
            unsigned pos = base + atomicAdd(&cur[w4.z >> DST_SHIFT], 1u);
            csr_src[pos] = w4.z & SRC_MASK;
        }
        if (w4.w != SENTINEL) {
            unsigned pos = base + atomicAdd(&cur[w4.w >> DST_SHIFT], 1u);
            csr_src[pos] = w4.w & SRC_MASK;
        }
    }
}

// Standalone node1 (fallback path only).
static __global__ void node1_kernel(const float* __restrict__ x, const float* __restrict__ dinv,
                                    char* __restrict__ xs, int n_nodes) {
    int i = blockIdx.x * blockDim.x + threadIdx.x;
    if (i >= n_nodes) return;
    float di = dinv[i];
    unsigned w[5];
#pragma unroll
    for (int j = 0; j < 5; j++) {
        unsigned lo = __half_as_ushort(__float2half_rn(x[(size_t)i * 10 + 2 * j] * di));
        unsigned hi = __half_as_ushort(__float2half_rn(x[(size_t)i * 10 + 2 * j + 1] * di));
        w[j] = lo | (hi << 16);
    }
    char* row = xs + (size_t)i * XS_BYTES;
    *(uint4*)row = make_uint4(w[0], w[1], w[2], w[3]);
    *(uint2*)(row + 16) = make_uint2(w[4], 0u);
}

// Layer-1 gather + dense 10->16->relu->2 fused. 16 lanes per node; 2x unroll.
static __global__ void gather1_kernel(const unsigned int* __restrict__ row_start,
                                      const unsigned int* __restrict__ cnt,
                                      const unsigned int* __restrict__ csr_src,
                                      const char* __restrict__ xs,
                                      const float* __restrict__ dinv,
                                      const float* __restrict__ W1, const float* __restrict__ b1,
                                      const float* __restrict__ W2,
                                      float* __restrict__ gs, int n_nodes) {
    __shared__ float sW1[160];
    __shared__ float sb1[16];
    __shared__ float sW2[32];
    for (int k = threadIdx.x; k < 160; k += blockDim.x) sW1[k] = W1[k];
    if (threadIdx.x < 16) sb1[threadIdx.x] = b1[threadIdx.x];
    if (threadIdx.x < 32) sW2[threadIdx.x] = W2[threadIdx.x];
    __syncthreads();
    int node = blockIdx.x * (blockDim.x >> 4) + (threadIdx.x >> 4);
    int lg = threadIdx.x & 15;
    if (node >= n_nodes) return;
    unsigned start = row_start[node];
    unsigned degn = cnt[node];
    float acc[10];
#pragma unroll
    for (int j = 0; j < 10; j++) acc[j] = 0.f;
    for (unsigned k = lg; k < degn; k += 32) {
        unsigned s0 = csr_src[start + k];
        unsigned k1 = k + 16;
        bool v1 = k1 < degn;
        unsigned s1 = v1 ? csr_src[start + k1] : s0;
        const char* r0 = xs + (size_t)s0 * XS_BYTES;
        const char* r1 = xs + (size_t)s1 * XS_BYTES;
        uint4 a0 = *(const uint4*)r0;
        unsigned b0 = *(const unsigned*)(r0 + 16);
        uint4 a1 = *(const uint4*)r1;
        unsigned b1w = *(const unsigned*)(r1 + 16);
        float2 f;
        f = h2f(a0.x); acc[0] += f.x; acc[1] += f.y;
        f = h2f(a0.y); acc[2] += f.x; acc[3] += f.y;
        f = h2f(a0.z); acc[4] += f.x; acc[5] += f.y;
        f = h2f(a0.w); acc[6] += f.x; acc[7] += f.y;
        f = h2f(b0);   acc[8] += f.x; acc[9] += f.y;
        if (v1) {
            f = h2f(a1.x); acc[0] += f.x; acc[1] += f.y;
            f = h2f(a1.y); acc[2] += f.x; acc[3] += f.y;
            f = h2f(a1.z); acc[4] += f.x; acc[5] += f.y;
            f = h2f(a1.w); acc[6] += f.x; acc[7] += f.y;
            f = h2f(b1w);  acc[8] += f.x; acc[9] += f.y;
        }
    }
    if (lg == 0) {   // self-loop contribution
        const char* row = xs + (size_t)node * XS_BYTES;
        uint4 a = *(const uint4*)row;
        unsigned b = *(const unsigned*)(row + 16);
        float2 f;
        f = h2f(a.x); acc[0] += f.x; acc[1] += f.y;
        f = h2f(a.y); acc[2] += f.x; acc[3] += f.y;
        f = h2f(a.z); acc[4] += f.x; acc[5] += f.y;
        f = h2f(a.w); acc[6] += f.x; acc[7] += f.y;
        f = h2f(b);   acc[8] += f.x; acc[9] += f.y;
    }
#pragma unroll
    for (int off = 8; off > 0; off >>= 1) {
#pragma unroll
        for (int j = 0; j < 10; j++) acc[j] += __shfl_xor(acc[j], off);
    }
    float di = dinv[node];
    float h = sb1[lg];
#pragma unroll
    for (int k = 0; k < 10; k++) h = fmaf(acc[k] * di, sW1[k * 16 + lg], h);
    h = fmaxf(h, 0.f);
    float g0 = h * sW2[lg * 2 + 0];
    float g1 = h * sW2[lg * 2 + 1];
#pragma unroll
    for (int off = 8; off > 0; off >>= 1) {
        g0 += __shfl_xor(g0, off);
        g1 += __shfl_xor(g1, off);
    }
    if (lg == 0) {
        float2 o;
        o.x = g0 * di;
        o.y = g1 * di;
        ((float2*)gs)[node] = o;
    }
}

// Layer-2 gather + final scale + bias. 16 lanes per node; 4x unroll.
static __global__ void gather2_kernel(const unsigned int* __restrict__ row_start,
                                      const unsigned int* __restrict__ cnt,
                                      const unsigned int* __restrict__ csr_src,
                                      const float* __restrict__ gs,
                                      const float* __restrict__ dinv,
                                      const float* __restrict__ b2,
                                      float* __restrict__ out, int n_nodes) {
    int node = blockIdx.x * (blockDim.x >> 4) + (threadIdx.x >> 4);
    int lg = threadIdx.x & 15;
    if (node >= n_nodes) return;
    unsigned start = row_start[node];
    unsigned degn = cnt[node];
    float a0 = 0.f, a1 = 0.f;
    const float2* G = (const float2*)gs;
    for (unsigned k = lg; k < degn; k += 64) {
        unsigned k1 = k + 16, k2 = k + 32, k3 = k + 48;
        bool v1 = k1 < degn, v2 = k2 < degn, v3 = k3 < degn;
        unsigned s0 = csr_src[start + k];
        unsigned s1 = v1 ? csr_src[start + k1] : s0;
        unsigned s2 = v2 ? csr_src[start + k2] : s0;
        unsigned s3 = v3 ? csr_src[start + k3] : s0;
        float2 w0 = G[s0];
        float2 w1 = G[s1];
        float2 w2 = G[s2];
        float2 w3 = G[s3];
        a0 += w0.x; a1 += w0.y;
        if (v1) { a0 += w1.x; a1 += w1.y; }
        if (v2) { a0 += w2.x; a1 += w2.y; }
        if (v3) { a0 += w3.x; a1 += w3.y; }
    }
    if (lg == 0) {   // self loop
        float2 s = G[node];
        a0 += s.x; a1 += s.y;
    }
#pragma unroll
    for (int off = 8; off > 0; off >>= 1) {
        a0 += __shfl_xor(a0, off);
        a1 += __shfl_xor(a1, off);
    }
    if (lg == 0) {
        float di = dinv[node];
        float2 o;
        o.x = fmaf(a0, di, b2[0]);
        o.y = fmaf(a1, di, b2[1]);
        ((float2*)out)[node] = o;
    }
}

// ---------------- fallback (atomic-CSR build) -------------------------------
static __global__ void deg_kernel(const void* __restrict__ ei, const int* __restrict__ flag,
                                  unsigned int* __restrict__ cnt, int n_edges) {
    const int is64 = *flag;
    unsigned stride = gridDim.x * blockDim.x;
    for (unsigned e = blockIdx.x * blockDim.x + threadIdx.x; e < (unsigned)n_edges; e += stride) {
        int d = nt_dst(ei, is64, n_edges, e);
        atomicAdd(&cnt[d], 1u);
    }
}
static __global__ void alloc_kernel(const unsigned int* __restrict__ cnt,
                                    unsigned int* __restrict__ row_start,
                                    unsigned int* __restrict__ cursor,
                                    unsigned int* __restrict__ gcur,
                                    float* __restrict__ dinv, int n_nodes) {
    __shared__ unsigned wsum[4];
    int i = blockIdx.x * blockDim.x + threadIdx.x;
    int lane = threadIdx.x & 63;
    int wid = threadIdx.x >> 6;
    unsigned d = (i < n_nodes) ? cnt[i] : 0u;
    unsigned scan = d;
#pragma unroll
    for (int off = 1; off < 64; off <<= 1) {
        unsigned t = __shfl_up(scan, off);
        if (lane >= off) scan += t;
    }
    if (lane == 63) wsum[wid] = scan;
    __syncthreads();
    if (threadIdx.x == 0) {
        unsigned s0 = wsum[0], s1 = wsum[1], s2 = wsum[2], s3 = wsum[3];
        unsigned base = atomicAdd(gcur, s0 + s1 + s2 + s3);
        wsum[0] = base;
        wsum[1] = base + s0;
        wsum[2] = base + s0 + s1;
        wsum[3] = base + s0 + s1 + s2;
    }
    __syncthreads();
    if (i < n_nodes) {
        unsigned pos = wsum[wid] + scan - d;
        row_start[i] = pos;
        cursor[i] = pos;
        dinv[i] = rsqrtf((float)(d + 1u));
    }
}
static __global__ void csrfill_kernel(const void* __restrict__ ei, const int* __restrict__ flag,
                                      unsigned int* __restrict__ cursor,
                                      unsigned int* __restrict__ csr_src, int n_edges) {
    const int is64 = *flag;
    unsigned stride = gridDim.x * blockDim.x;
    for (unsigned e = blockIdx.x * blockDim.x + threadIdx.x; e < (unsigned)n_edges; e += stride) {
        int s = nt_src(ei, is64, n_edges, e);
        int d = nt_dst(ei, is64, n_edges, e);
        unsigned pos = atomicAdd(&cursor[d], 1u);
        csr_src[pos] = (unsigned)s;
    }
}

static inline char* align_up(char* p, size_t a) {
    return (char*)(((uintptr_t)p + a - 1) & ~(uintptr_t)(a - 1));
}

extern "C" void kernel_launch(void* const* d_in, const int* in_sizes, int n_in,
                              void* d_out, int out_size, void* d_ws, size_t ws_size,
                              hipStream_t stream) {
    const float* x  = (const float*)d_in[0];
    const void*  ei = d_in[1];
    const float* W1 = (const float*)d_in[2];
    const float* b1 = (const float*)d_in[3];
    const float* W2 = (const float*)d_in[4];
    const float* b2 = (const float*)d_in[5];
    float* out = (float*)d_out;

    const int n_nodes = in_sizes[0] / 10;
    const int n_edges = in_sizes[1] / 2;
    (void)n_in; (void)out_size;

    const int nbuckets = (n_nodes + BKT_SZ - 1) >> BKT_BITS;
    const bool pack_ok = (n_nodes <= (1 << 17)) && (nbuckets <= NBK);
    // per-bucket region capacity: 1.25x mean + 2048, 16-aligned (~48 sigma slack)
    const unsigned cap = (unsigned)(((((size_t)n_edges / (size_t)(nbuckets > 0 ? nbuckets : 1)) * 5 / 4)
                                     + 2048 + 15) & ~(size_t)15);
    const size_t region_words = (size_t)nbuckets * cap + 64;

    char* p = (char*)d_ws;
    int* flag = (int*)p;
    unsigned* gcur = (unsigned*)(p + 64);
    p += 256;
    // common node buffers (each 256B-aligned)
    unsigned* row_start = (unsigned*)p; p = align_up(p + (size_t)n_nodes * 4, 256);
    unsigned* cnt = (unsigned*)p;       p = align_up(p + (size_t)n_nodes * 4, 256);
    float* dinv = (float*)p;            p = align_up(p + (size_t)n_nodes * 4, 256);
    float* gs = (float*)p;              p = align_up(p + (size_t)n_nodes * 8, 256);
    char* xs = p;                       p = align_up(p + (size_t)n_nodes * XS_BYTES, 256);

    const size_t head_bytes = (size_t)(p - (char*)d_ws);
    const size_t need_new = head_bytes + 2 * (region_words * 4 + 256) + NBK * 4 + 256;
    const size_t need_old = head_bytes + (size_t)n_edges * 4 + 256 +
                            (size_t)n_nodes * 4 + 256;

    const int NODES_PER_BLK = 256 / 16;  // 16-lane groups, 256-thread blocks
    const int gblocks = (n_nodes + NODES_PER_BLK - 1) / NODES_PER_BLK;

    if (pack_ok && ws_size >= need_new) {
        unsigned* csr_src = (unsigned*)p;  p = align_up(p + region_words * 4, 256);
        unsigned* gbase = (unsigned*)p;    p = align_up(p + (size_t)NBK * 4, 256);
        unsigned* bucketed = (unsigned*)p; p = align_up(p + region_words * 4, 256);

        const int nblocksB = (int)(((unsigned)n_edges + CHUNK - 1) / CHUNK);

        detect_init_kernel<<<1, 256, 0, stream>>>((const unsigned int*)ei, flag, gbase, cap);
        scatterB_kernel<<<nblocksB, TPB_A, 0, stream>>>(ei, flag, gbase, bucketed, n_edges, cap);
        passB_kernel<<<nbuckets, TPB_B, 0, stream>>>(bucketed, gbase, cap, x, csr_src,
                                                     row_start, cnt, dinv, xs, n_nodes);
        gather1_kernel<<<gblocks, 256, 0, stream>>>(row_start, cnt, csr_src, xs, dinv,
                                                    W1, b1, W2, gs, n_nodes);
        gather2_kernel<<<gblocks, 256, 0, stream>>>(row_start, cnt, csr_src, gs, dinv,
                                                    b2, out, n_nodes);
    } else if (ws_size >= need_old) {
        unsigned* csr_src = (unsigned*)p; p = align_up(p + (size_t)n_edges * 4, 256);
        unsigned* cursor = (unsigned*)p;

        hipMemsetAsync(d_ws, 0, 256, stream);
        hipMemsetAsync(cnt, 0, (size_t)n_nodes * 4, stream);
        detect_init_kernel<<<1, 256, 0, stream>>>((const unsigned int*)ei, flag, cnt, 0u);
        deg_kernel<<<2048, 256, 0, stream>>>(ei, flag, cnt, n_edges);
        alloc_kernel<<<(n_nodes + 255) / 256, 256, 0, stream>>>(cnt, row_start, cursor, gcur, dinv, n_nodes);
        csrfill_kernel<<<4096, 256, 0, stream>>>(ei, flag, cursor, csr_src, n_edges);
        node1_kernel<<<(n_nodes + 255) / 256, 256, 0, stream>>>(x, dinv, xs, n_nodes);
        gather1_kernel<<<gblocks, 256, 0, stream>>>(row_start, cnt, csr_src, xs, dinv,
                                                    W1, b1, W2, gs, n_nodes);
        gather2_kernel<<<gblocks, 256, 0, stream>>>(row_start, cnt, csr_src, gs, dinv,
                                                    b2, out, n_nodes);
    }
}